// Round 12
// baseline (140.768 us; speedup 1.0000x reference)
//
#include <hip/hip_runtime.h>

// ---------------------------------------------------------------------------
// GraphSAGE 2-layer forward, bf16 MFMA.
// Pipeline: misc (W pack + pads) -> mean_stream (mean10 -> M1, lvl1 bf16 -> S1)
//           -> gemm0_hybrid -> agg1_pack -> gemm1.
// == Round 9 config, plus L3-budgeted NT/plain split of the lvl2 stream ==
// Plain (cacheable, retained across replays): xdst2 (51 MB), xneg2 mean-rows
// >= 7680 (102 MB), lvl1 (36 MB), lvl0 (4 MB), intermediates (~51 MB) -> ~246 MB < 256 MB L3.
// NT (streamed): xsrc2 + xneg2 mean-rows < 7680 (~205 MB).
// ---------------------------------------------------------------------------

typedef __attribute__((ext_vector_type(8))) short bhalf8;
typedef __attribute__((ext_vector_type(4))) float floatx4;

__device__ __forceinline__ ushort f2bf(float f) {
  uint32_t u = __float_as_uint(f);
  return (ushort)((u + 0x7fffu + ((u >> 16) & 1u)) >> 16);
}
__device__ __forceinline__ float bf2f(ushort u) {
  return __uint_as_float(((uint32_t)u) << 16);
}
__device__ __forceinline__ void gll16(const void* g, void* l) {
  __builtin_amdgcn_global_load_lds((const __attribute__((address_space(1))) void*)g,
                                   (__attribute__((address_space(3))) void*)l, 16, 0, 0);
}

// ------- misc: grid 1721 = 1280 (W pack) | 231 (M1 pad) | 210 (S1 pad) ------
__global__ __launch_bounds__(256) void misc_k(const float* __restrict__ W0, const float* __restrict__ W1,
                                              ushort* __restrict__ W0p, ushort* __restrict__ W1p,
                                              ushort* __restrict__ M1, ushort* __restrict__ S1) {
  const int b = blockIdx.x, tid = threadIdx.x;
  if (b < 1280) {
    const int idx = b * 256 + tid;
    if (idx < 262144) {  // W0p: [kstp(32)][kg(4)][n(256)][i(8)]
      const int i = idx & 7, n = (idx >> 3) & 255, kgv = (idx >> 11) & 3, kstp = idx >> 13;
      const int k = kstp * 32 + kgv * 8 + i;
      int srcr;
      if (k < 512) srcr = (k < 500) ? k : -1;
      else { const int k2 = k - 512; srcr = (k2 < 500) ? 500 + k2 : -1; }
      W0p[idx] = (srcr >= 0) ? f2bf(W0[srcr * 256 + n]) : (ushort)0;
    } else {             // W1p: [kstp(16)][kg(4)][n(128)][i(8)]
      const int j = idx - 262144;
      const int i = j & 7, n = (j >> 3) & 127, kgv = (j >> 10) & 3, kstp = j >> 12;
      const int k = kstp * 32 + kgv * 8 + i;
      W1p[j] = f2bf(W1[k * 128 + n]);
    }
  } else if (b < 1511) {  // M1 pad cols [125,128) f4 over 19712 rows
    const int p = (b - 1280) * 256 + tid;  // < 59136
    const int r = p / 3, sl = p - r * 3;
    ushort4 z; z.x = 0; z.y = 0; z.z = 0; z.w = 0;
    ((ushort4*)M1)[(long)r * 128 + 125 + sl] = z;
  } else {                // S1 pad cols [125,128) f4 over 17920 rows
    const int p = (b - 1511) * 256 + tid;  // < 53760
    const int r = p / 3, sl = p - r * 3;
    ushort4 z; z.x = 0; z.y = 0; z.z = 0; z.w = 0;
    ((ushort4*)S1)[(long)r * 128 + 125 + sl] = z;
  }
}

// ------- mean_stream: items = output f4 cols, order lvl2 then lvl1 ----------
// slots p=0..5 -> {src1o(xsrc2), dst1o(xdst2), neg1o(xneg2); src0o,dst0o,neg0o from lvl1}
// itemEnd {320000,640000,2240000,2272000,2304000,2464000}; HALF=1232000.
// Thread does items i and i+HALF. lvl1 items (p>=3) side-write bf16 rows to S1.
// NT policy: NT iff (p==0) or (p==2 && mean-row < 7680); else plain (L3-budget).
struct MSP {
  const float* src[6];   // {xsrc2,xdst2,xneg2,xsrc1,xdst1,xneg1}
  long itemEnd[6];
  int outRow[6];         // {256,3072,6912,0,2816,5632}
  int s1Off[6];          // {0,0,0,0,2560,5120}
};

__global__ __launch_bounds__(256, 4) void mean_stream(MSP P, ushort* __restrict__ M1,
                                                      ushort* __restrict__ S1) {
  long i = (long)blockIdx.x * 256 + threadIdx.x;
  if (i >= 1232000) i = 1231999;
  // item1 (always lvl2)
  int p1 = 0;
#pragma unroll
  for (int t = 0; t < 2; ++t) p1 = (i >= P.itemEnd[t]) ? t + 1 : p1;
  const long b1 = p1 ? P.itemEnd[p1 - 1] : 0;
  const int l1 = (int)(i - b1);
  const int r1 = l1 / 125, j1 = l1 - r1 * 125;
  const floatx4* __restrict__ sp1 = (const floatx4*)P.src[p1] + (long)r1 * 1250 + j1;
  // item2
  const long i2 = i + 1232000;
  int p2 = 2;
#pragma unroll
  for (int t = 2; t < 5; ++t) p2 = (i2 >= P.itemEnd[t]) ? t + 1 : p2;
  const long b2 = P.itemEnd[p2 - 1];
  const int l2 = (int)(i2 - b2);
  const int r2 = l2 / 125, j2 = l2 - r2 * 125;
  const floatx4* __restrict__ sp2 = (const floatx4*)P.src[p2] + (long)r2 * 1250 + j2;

  floatx4 t1[10], t2[10];
  const bool nt1 = (p1 == 0) || (p1 == 2 && r1 < 7680);
  if (nt1) {
#pragma unroll
    for (int k = 0; k < 10; ++k) t1[k] = __builtin_nontemporal_load(sp1 + (long)k * 125);
  } else {
#pragma unroll
    for (int k = 0; k < 10; ++k) t1[k] = sp1[(long)k * 125];
  }
  const bool nt2 = (p2 == 2) && (r2 < 7680);
  if (nt2) {
#pragma unroll
    for (int k = 0; k < 10; ++k) t2[k] = __builtin_nontemporal_load(sp2 + (long)k * 125);
  } else {
#pragma unroll
    for (int k = 0; k < 10; ++k) t2[k] = sp2[(long)k * 125];
  }

  const floatx4 a1 =
      ((((t1[0] + t1[1]) + (t1[2] + t1[3])) + ((t1[4] + t1[5]) + (t1[6] + t1[7]))) + (t1[8] + t1[9])) * 0.1f;
  ushort4 o1;
  o1.x = f2bf(a1.x); o1.y = f2bf(a1.y); o1.z = f2bf(a1.z); o1.w = f2bf(a1.w);
  ((ushort4*)M1)[((long)P.outRow[p1] + r1) * 128 + j1] = o1;

  const bool lvl1 = p2 >= 3;
  if (lvl1) {  // side-write bf16 casts of the 10 lvl1 rows into S1
    const long srow = (long)P.s1Off[p2] + (long)r2 * 10;
#pragma unroll
    for (int k = 0; k < 10; ++k) {
      ushort4 c;
      c.x = f2bf(t2[k].x); c.y = f2bf(t2[k].y); c.z = f2bf(t2[k].z); c.w = f2bf(t2[k].w);
      ((ushort4*)S1)[(srow + k) * 128 + j2] = c;
    }
  }
  const floatx4 a2 =
      ((((t2[0] + t2[1]) + (t2[2] + t2[3])) + ((t2[4] + t2[5]) + (t2[6] + t2[7]))) + (t2[8] + t2[9])) * 0.1f;
  ushort4 o2;
  o2.x = f2bf(a2.x); o2.y = f2bf(a2.y); o2.z = f2bf(a2.z); o2.w = f2bf(a2.w);
  ((ushort4*)M1)[((long)P.outRow[p2] + r2) * 128 + j2] = o2;
}

// ------- gemm0_hybrid: H1 = relu([self | M1] @ W0p), 128x128 tile -----------
struct G0P {
  const void* selfp[6];  // {xsrc0, S1+0, xdst0, S1+2560*512, xneg0, S1+5120*512}
  int tileEnd[6];        // {2,22,24,44,54,154}
};

__global__ __launch_bounds__(256) void gemm0_hybrid(G0P P, const ushort* __restrict__ M1,
                                                    const ushort* __restrict__ W0p,
                                                    ushort* __restrict__ H1) {
  __shared__ ushort As[128 * 32];
  __shared__ ushort Bs[128 * 32];

  const int tid = threadIdx.x;
  const int wid = tid >> 6, l = tid & 63;
  const int wr = wid >> 1, wc = wid & 1;
  const int lr = l & 15, kg = l >> 4;

  const int bt = blockIdx.x;
  const int n0 = blockIdx.y * 128;
  int s = 0;
#pragma unroll
  for (int t = 0; t < 5; ++t) s = (bt >= P.tileEnd[t]) ? t + 1 : s;
  const int tb = s ? P.tileEnd[s - 1] : 0;
  const long lrow0 = (long)(bt - tb) * 128;
  const long row0 = (long)bt * 128;

  const int srow = tid >> 1, half = tid & 1;
  const floatx4* __restrict__ selfF4 = (const floatx4*)P.selfp[s] + (lrow0 + srow) * 125;
  const ushort* __restrict__ selfB = (const ushort*)P.selfp[s] + (lrow0 + srow) * 512;
  const int swr = (srow >> 1) & 3;
  const int kg0 = half * 2;

  int aoff[4], boff[4];
#pragma unroll
  for (int mi = 0; mi < 4; ++mi) {
    const int row = wr * 64 + mi * 16 + lr;
    aoff[mi] = row * 64 + ((kg ^ ((row >> 1) & 3)) << 4);
  }
#pragma unroll
  for (int ni = 0; ni < 4; ++ni) boff[ni] = (kg * 128 + wc * 64 + ni * 16 + lr) << 4;

  floatx4 acc[4][4];
#pragma unroll
  for (int mi = 0; mi < 4; ++mi)
#pragma unroll
    for (int ni = 0; ni < 4; ++ni) acc[mi][ni] = (floatx4){0.f, 0.f, 0.f, 0.f};

  for (int ks = 0; ks < 32; ++ks) {
    __syncthreads();
    if (ks < 16) {
      bhalf8 c0, c1;
      if (!(s & 1)) {  // lvl0: fp32 + cvt
        const int f0 = ks * 8 + half * 4;
        floatx4 v[4];
#pragma unroll
        for (int q = 0; q < 4; ++q) {
          const int fi = f0 + q;
          v[q] = selfF4[(fi > 124) ? 124 : fi];
        }
        ushort h[16];
#pragma unroll
        for (int q = 0; q < 4; ++q) {
          const bool ok = (f0 + q) <= 124;
#pragma unroll
          for (int e = 0; e < 4; ++e) h[q * 4 + e] = ok ? f2bf(v[q][e]) : (ushort)0;
        }
#pragma unroll
        for (int e = 0; e < 8; ++e) { c0[e] = (short)h[e]; c1[e] = (short)h[8 + e]; }
      } else {         // lvl1: S1 bf16 direct (zero-padded)
        const int u0 = (ks * 8 + half * 4) * 4;
        c0 = *(const bhalf8*)(selfB + u0);
        c1 = *(const bhalf8*)(selfB + u0 + 8);
      }
      *(bhalf8*)((char*)As + srow * 64 + ((kg0 ^ swr) << 4)) = c0;
      *(bhalf8*)((char*)As + srow * 64 + (((kg0 + 1) ^ swr) << 4)) = c1;
    } else {
      const int k0 = (ks - 16) * 32;
#pragma unroll
      for (int it = 0; it < 2; ++it) {
        const int o = it * 4096 + tid * 16;
        const int row = o >> 6;
        const int sw = (o >> 4) & 3;
        const int kgs = sw ^ ((row >> 1) & 3);
        const ushort* g = M1 + (row0 + row) * (size_t)512 + (k0 + kgs * 8);
        gll16(g, (char*)As + it * 4096 + wid * 1024);
      }
    }
#pragma unroll
    for (int it = 0; it < 2; ++it) {
      const int cell = it * 256 + tid;
      const int bkg = cell >> 7;
      const int n = cell & 127;
      const ushort* g = W0p + ((size_t)(ks * 4 + bkg) * 256 + (n0 + n)) * 8;
      gll16(g, (char*)Bs + it * 4096 + wid * 1024);
    }
    __syncthreads();

    bhalf8 af[4], bfr[4];
#pragma unroll
    for (int mi = 0; mi < 4; ++mi) af[mi] = *(const bhalf8*)((const char*)As + aoff[mi]);
#pragma unroll
    for (int ni = 0; ni < 4; ++ni) bfr[ni] = *(const bhalf8*)((const char*)Bs + boff[ni]);
#pragma unroll
    for (int mi = 0; mi < 4; ++mi)
#pragma unroll
      for (int ni = 0; ni < 4; ++ni)
        acc[mi][ni] = __builtin_amdgcn_mfma_f32_16x16x32_bf16(af[mi], bfr[ni], acc[mi][ni], 0, 0, 0);
  }

#pragma unroll
  for (int mi = 0; mi < 4; ++mi)
#pragma unroll
    for (int ni = 0; ni < 4; ++ni) {
      const floatx4 v = acc[mi][ni];
      const int gcol = n0 + wc * 64 + ni * 16 + lr;
#pragma unroll
      for (int r = 0; r < 4; ++r) {
        const long grow = row0 + wr * 64 + mi * 16 + kg * 4 + r;
        H1[grow * 256 + gcol] = f2bf(fmaxf(v[r], 0.f));
      }
    }
}

// ---------------- agg1: H1 bf16 -> A2 [1792][512] bf16 (self | mean10) -------
__global__ __launch_bounds__(256) void agg1_pack(const ushort* __restrict__ H1, ushort* __restrict__ A2,
                                                 long total) {
  const long stride = (long)gridDim.x * 256;
  for (long idx = (long)blockIdx.x * 256 + threadIdx.x; idx < total; idx += stride) {
    const bool g1 = idx >= 32768, g2 = idx >= 65536;
    const long base = g2 ? 65536 : (g1 ? 32768 : 0);
    const int selfo = g2 ? 5632 : (g1 ? 2816 : 0);
    const int neigho = g2 ? 6912 : (g1 ? 3072 : 256);
    const int outo = g2 ? 512 : (g1 ? 256 : 0);
    const long li = idx - base;
    const long r = li >> 7;
    const int c = (int)(li & 127);
    const ushort4* H = (const ushort4*)H1;
    ushort4 ov;
    if (c < 64) {
      ov = H[((long)selfo + r) * 64 + c];
    } else {
      const int j = c - 64;
      float ax = 0.f, ay = 0.f, az = 0.f, aw = 0.f;
#pragma unroll
      for (int k = 0; k < 10; ++k) {
        const ushort4 v = H[((long)neigho + r * 10 + k) * 64 + j];
        ax += bf2f(v.x); ay += bf2f(v.y); az += bf2f(v.z); aw += bf2f(v.w);
      }
      ov.x = f2bf(ax * 0.1f); ov.y = f2bf(ay * 0.1f);
      ov.z = f2bf(az * 0.1f); ov.w = f2bf(aw * 0.1f);
    }
    ((ushort4*)A2)[((long)outo + r) * 128 + c] = ov;
  }
}

// ---------------- MFMA GEMM (layer1): C = relu(A @ Bpacked) ------------------
template <int BM, int BN, int MI, int NI, bool OUT_BF16>
__global__ __launch_bounds__(256) void gemm_mfma(const ushort* __restrict__ A,
                                                 const ushort* __restrict__ Bp,
                                                 void* __restrict__ Cout, int K, int Nfull) {
  __shared__ ushort As[BM * 32];
  __shared__ ushort Bs[BN * 32];

  const int tid = threadIdx.x;
  const int wid = tid >> 6, l = tid & 63;
  const int wr = wid >> 1, wc = wid & 1;
  const int lr = l & 15, kg = l >> 4;
  const long row0 = (long)blockIdx.x * BM;
  const int n0 = blockIdx.y * BN;

  int aoff[MI], boff[NI];
#pragma unroll
  for (int mi = 0; mi < MI; ++mi) {
    const int row = wr * (MI * 16) + mi * 16 + lr;
    aoff[mi] = row * 64 + ((kg ^ ((row >> 1) & 3)) << 4);
  }
#pragma unroll
  for (int ni = 0; ni < NI; ++ni) {
    const int cell = kg * BN + wc * (NI * 16) + ni * 16 + lr;
    boff[ni] = cell << 4;
  }

  floatx4 acc[MI][NI];
#pragma unroll
  for (int mi = 0; mi < MI; ++mi)
#pragma unroll
    for (int ni = 0; ni < NI; ++ni) acc[mi][ni] = (floatx4){0.f, 0.f, 0.f, 0.f};

  const int ksteps = K >> 5;
  for (int ks = 0; ks < ksteps; ++ks) {
    const int k0 = ks << 5;
    __syncthreads();
#pragma unroll
    for (int it = 0; it < (BM * 64) / 4096; ++it) {
      const int o = it * 4096 + tid * 16;
      const int row = o >> 6;
      const int sw = (o >> 4) & 3;
      const int kgs = sw ^ ((row >> 1) & 3);
      const ushort* g = A + (row0 + row) * (size_t)K + (k0 + kgs * 8);
      gll16(g, (char*)As + it * 4096 + wid * 1024);
    }
#pragma unroll
    for (int it = 0; it < (BN * 64) / 4096; ++it) {
      const int cell = it * 256 + tid;
      const int bkg = cell / BN;
      const int n = cell & (BN - 1);
      const ushort* g = Bp + ((size_t)(ks * 4 + bkg) * Nfull + (n0 + n)) * 8;
      gll16(g, (char*)Bs + it * 4096 + wid * 1024);
    }
    __syncthreads();

    bhalf8 af[MI], bf[NI];
#pragma unroll
    for (int mi = 0; mi < MI; ++mi) af[mi] = *(const bhalf8*)((const char*)As + aoff[mi]);
#pragma unroll
    for (int ni = 0; ni < NI; ++ni) bf[ni] = *(const bhalf8*)((const char*)Bs + boff[ni]);
#pragma unroll
    for (int mi = 0; mi < MI; ++mi)
#pragma unroll
      for (int ni = 0; ni < NI; ++ni)
        acc[mi][ni] = __builtin_amdgcn_mfma_f32_16x16x32_bf16(af[mi], bf[ni], acc[mi][ni], 0, 0, 0);
  }

#pragma unroll
  for (int mi = 0; mi < MI; ++mi)
#pragma unroll
    for (int ni = 0; ni < NI; ++ni) {
      const floatx4 v = acc[mi][ni];
      const int gcol = n0 + wc * (NI * 16) + ni * 16 + lr;
#pragma unroll
      for (int r = 0; r < 4; ++r) {
        const long grow = row0 + wr * (MI * 16) + mi * 16 + kg * 4 + r;
        const float x = fmaxf(v[r], 0.f);
        if (OUT_BF16)
          ((ushort*)Cout)[grow * Nfull + gcol] = f2bf(x);
        else
          ((float*)Cout)[grow * Nfull + gcol] = x;
      }
    }
}

extern "C" void kernel_launch(void* const* d_in, const int* in_sizes, int n_in,
                              void* d_out, int out_size, void* d_ws, size_t ws_size,
                              hipStream_t stream) {
  const float* xsrc0 = (const float*)d_in[0];
  const float* xdst0 = (const float*)d_in[1];
  const float* xneg0 = (const float*)d_in[2];
  const float* xsrc1 = (const float*)d_in[3];
  const float* xdst1 = (const float*)d_in[4];
  const float* xneg1 = (const float*)d_in[5];
  const float* xsrc2 = (const float*)d_in[6];
  const float* xdst2 = (const float*)d_in[7];
  const float* xneg2 = (const float*)d_in[8];
  const float* W0 = (const float*)d_in[9];
  const float* W1 = (const float*)d_in[10];
  float* out = (float*)d_out;

  // workspace (ushorts), 16B aligned:
  ushort* M1 = (ushort*)d_ws;        // 19712*512 = 10,092,544
  ushort* S1 = M1 + 10092544;        // 17920*512 =  9,175,040
  ushort* H1 = S1 + 9175040;         // 19712*256 =  5,046,272
  ushort* A2 = H1 + 5046272;         // 1792*512  =    917,504
  ushort* W0p = A2 + 917504;         // 262,144
  ushort* W1p = W0p + 262144;        // 65,536   (total ~51 MB)

  misc_k<<<dim3(1721), dim3(256), 0, stream>>>(W0, W1, W0p, W1p, M1, S1);

  // ---- mean stream (lvl2 first, lvl1 last + S1 side-write) ----
  {
    MSP p;
    const float* srcs[6] = {xsrc2, xdst2, xneg2, xsrc1, xdst1, xneg1};
    static const long itemEnd[6] = {320000, 640000, 2240000, 2272000, 2304000, 2464000};
    static const int outRow[6] = {256, 3072, 6912, 0, 2816, 5632};
    static const int s1Off[6] = {0, 0, 0, 0, 2560, 5120};
    for (int j = 0; j < 6; ++j) {
      p.src[j] = srcs[j];
      p.itemEnd[j] = itemEnd[j];
      p.outRow[j] = outRow[j];
      p.s1Off[j] = s1Off[j];
    }
    mean_stream<<<dim3(4813), dim3(256), 0, stream>>>(p, M1, S1);
  }

  // ---- layer0 GEMM (hybrid A) ----
  {
    G0P g;
    g.selfp[0] = xsrc0;
    g.selfp[1] = S1;
    g.selfp[2] = xdst0;
    g.selfp[3] = S1 + (size_t)2560 * 512;
    g.selfp[4] = xneg0;
    g.selfp[5] = S1 + (size_t)5120 * 512;
    static const int tileEnd[6] = {2, 22, 24, 44, 54, 154};
    for (int j = 0; j < 6; ++j) g.tileEnd[j] = tileEnd[j];
    gemm0_hybrid<<<dim3(154, 2), dim3(256), 0, stream>>>(g, M1, W0p, H1);
  }

  // ---- layer1 agg + pack ----
  agg1_pack<<<dim3(896), dim3(256), 0, stream>>>(H1, A2, 229376);

  // ---- layer1 GEMM ----
  gemm_mfma<64, 64, 2, 2, false><<<dim3(28, 2), dim3(256), 0, stream>>>(A2, W1p, out, 512, 128);
}

// Round 13
// 140.460 us; speedup vs baseline: 1.0022x; 1.0022x over previous
//
#include <hip/hip_runtime.h>

// ---------------------------------------------------------------------------
// GraphSAGE 2-layer forward, bf16 MFMA.
// Pipeline: misc (W pack + pads) -> mean_stream (mean10 -> M1, lvl1 bf16 -> S1)
//           -> gemm0_hybrid -> agg1_pack -> gemm1.
// == Round 9 config + plain (cacheable) loads for xdst2 ONLY ==
// L3 budget: xdst2 51.2 + lvl1 36 + lvl0 3.6 + intermediates ~52 = ~143 MB < 256.
// NT: xsrc2 + xneg2 (307 MB). Ledger: R9 120.6 / R11 131.0 / R10 140.6 / R12 140.8.
// ---------------------------------------------------------------------------

typedef __attribute__((ext_vector_type(8))) short bhalf8;
typedef __attribute__((ext_vector_type(4))) float floatx4;

__device__ __forceinline__ ushort f2bf(float f) {
  uint32_t u = __float_as_uint(f);
  return (ushort)((u + 0x7fffu + ((u >> 16) & 1u)) >> 16);
}
__device__ __forceinline__ float bf2f(ushort u) {
  return __uint_as_float(((uint32_t)u) << 16);
}
__device__ __forceinline__ void gll16(const void* g, void* l) {
  __builtin_amdgcn_global_load_lds((const __attribute__((address_space(1))) void*)g,
                                   (__attribute__((address_space(3))) void*)l, 16, 0, 0);
}

// ------- misc: grid 1721 = 1280 (W pack) | 231 (M1 pad) | 210 (S1 pad) ------
__global__ __launch_bounds__(256) void misc_k(const float* __restrict__ W0, const float* __restrict__ W1,
                                              ushort* __restrict__ W0p, ushort* __restrict__ W1p,
                                              ushort* __restrict__ M1, ushort* __restrict__ S1) {
  const int b = blockIdx.x, tid = threadIdx.x;
  if (b < 1280) {
    const int idx = b * 256 + tid;
    if (idx < 262144) {  // W0p: [kstp(32)][kg(4)][n(256)][i(8)]
      const int i = idx & 7, n = (idx >> 3) & 255, kgv = (idx >> 11) & 3, kstp = idx >> 13;
      const int k = kstp * 32 + kgv * 8 + i;
      int srcr;
      if (k < 512) srcr = (k < 500) ? k : -1;
      else { const int k2 = k - 512; srcr = (k2 < 500) ? 500 + k2 : -1; }
      W0p[idx] = (srcr >= 0) ? f2bf(W0[srcr * 256 + n]) : (ushort)0;
    } else {             // W1p: [kstp(16)][kg(4)][n(128)][i(8)]
      const int j = idx - 262144;
      const int i = j & 7, n = (j >> 3) & 127, kgv = (j >> 10) & 3, kstp = j >> 12;
      const int k = kstp * 32 + kgv * 8 + i;
      W1p[j] = f2bf(W1[k * 128 + n]);
    }
  } else if (b < 1511) {  // M1 pad cols [125,128) f4 over 19712 rows
    const int p = (b - 1280) * 256 + tid;  // < 59136
    const int r = p / 3, sl = p - r * 3;
    ushort4 z; z.x = 0; z.y = 0; z.z = 0; z.w = 0;
    ((ushort4*)M1)[(long)r * 128 + 125 + sl] = z;
  } else {                // S1 pad cols [125,128) f4 over 17920 rows
    const int p = (b - 1511) * 256 + tid;  // < 53760
    const int r = p / 3, sl = p - r * 3;
    ushort4 z; z.x = 0; z.y = 0; z.z = 0; z.w = 0;
    ((ushort4*)S1)[(long)r * 128 + 125 + sl] = z;
  }
}

// ------- mean_stream: items = output f4 cols, order lvl2 then lvl1 ----------
// slots p=0..5 -> {src1o(xsrc2), dst1o(xdst2), neg1o(xneg2); src0o,dst0o,neg0o from lvl1}
// itemEnd {320000,640000,2240000,2272000,2304000,2464000}; HALF=1232000.
// Thread does items i and i+HALF. lvl1 items (p>=3) side-write bf16 rows to S1.
// NT policy: item1 NT unless p1==1 (xdst2, L3-retained); item2 NT iff lvl2.
struct MSP {
  const float* src[6];   // {xsrc2,xdst2,xneg2,xsrc1,xdst1,xneg1}
  long itemEnd[6];
  int outRow[6];         // {256,3072,6912,0,2816,5632}
  int s1Off[6];          // {0,0,0,0,2560,5120}
};

__global__ __launch_bounds__(256, 4) void mean_stream(MSP P, ushort* __restrict__ M1,
                                                      ushort* __restrict__ S1) {
  long i = (long)blockIdx.x * 256 + threadIdx.x;
  if (i >= 1232000) i = 1231999;
  // item1 (always lvl2)
  int p1 = 0;
#pragma unroll
  for (int t = 0; t < 2; ++t) p1 = (i >= P.itemEnd[t]) ? t + 1 : p1;
  const long b1 = p1 ? P.itemEnd[p1 - 1] : 0;
  const int l1 = (int)(i - b1);
  const int r1 = l1 / 125, j1 = l1 - r1 * 125;
  const floatx4* __restrict__ sp1 = (const floatx4*)P.src[p1] + (long)r1 * 1250 + j1;
  // item2
  const long i2 = i + 1232000;
  int p2 = 2;
#pragma unroll
  for (int t = 2; t < 5; ++t) p2 = (i2 >= P.itemEnd[t]) ? t + 1 : p2;
  const long b2 = P.itemEnd[p2 - 1];
  const int l2 = (int)(i2 - b2);
  const int r2 = l2 / 125, j2 = l2 - r2 * 125;
  const floatx4* __restrict__ sp2 = (const floatx4*)P.src[p2] + (long)r2 * 1250 + j2;

  floatx4 t1[10], t2[10];
  if (p1 != 1) {  // xsrc2 / xneg2: pure stream
#pragma unroll
    for (int k = 0; k < 10; ++k) t1[k] = __builtin_nontemporal_load(sp1 + (long)k * 125);
  } else {        // xdst2: cacheable, retained in L3 across replays
#pragma unroll
    for (int k = 0; k < 10; ++k) t1[k] = sp1[(long)k * 125];
  }
  const bool lvl1 = p2 >= 3;
  if (!lvl1) {
#pragma unroll
    for (int k = 0; k < 10; ++k) t2[k] = __builtin_nontemporal_load(sp2 + (long)k * 125);
  } else {        // lvl1: cacheable (36 MB, retained — R9 evidence)
#pragma unroll
    for (int k = 0; k < 10; ++k) t2[k] = sp2[(long)k * 125];
  }

  const floatx4 a1 =
      ((((t1[0] + t1[1]) + (t1[2] + t1[3])) + ((t1[4] + t1[5]) + (t1[6] + t1[7]))) + (t1[8] + t1[9])) * 0.1f;
  ushort4 o1;
  o1.x = f2bf(a1.x); o1.y = f2bf(a1.y); o1.z = f2bf(a1.z); o1.w = f2bf(a1.w);
  ((ushort4*)M1)[((long)P.outRow[p1] + r1) * 128 + j1] = o1;

  if (lvl1) {  // side-write bf16 casts of the 10 lvl1 rows into S1
    const long srow = (long)P.s1Off[p2] + (long)r2 * 10;
#pragma unroll
    for (int k = 0; k < 10; ++k) {
      ushort4 c;
      c.x = f2bf(t2[k].x); c.y = f2bf(t2[k].y); c.z = f2bf(t2[k].z); c.w = f2bf(t2[k].w);
      ((ushort4*)S1)[(srow + k) * 128 + j2] = c;
    }
  }
  const floatx4 a2 =
      ((((t2[0] + t2[1]) + (t2[2] + t2[3])) + ((t2[4] + t2[5]) + (t2[6] + t2[7]))) + (t2[8] + t2[9])) * 0.1f;
  ushort4 o2;
  o2.x = f2bf(a2.x); o2.y = f2bf(a2.y); o2.z = f2bf(a2.z); o2.w = f2bf(a2.w);
  ((ushort4*)M1)[((long)P.outRow[p2] + r2) * 128 + j2] = o2;
}

// ------- gemm0_hybrid: H1 = relu([self | M1] @ W0p), 128x128 tile -----------
struct G0P {
  const void* selfp[6];  // {xsrc0, S1+0, xdst0, S1+2560*512, xneg0, S1+5120*512}
  int tileEnd[6];        // {2,22,24,44,54,154}
};

__global__ __launch_bounds__(256) void gemm0_hybrid(G0P P, const ushort* __restrict__ M1,
                                                    const ushort* __restrict__ W0p,
                                                    ushort* __restrict__ H1) {
  __shared__ ushort As[128 * 32];
  __shared__ ushort Bs[128 * 32];

  const int tid = threadIdx.x;
  const int wid = tid >> 6, l = tid & 63;
  const int wr = wid >> 1, wc = wid & 1;
  const int lr = l & 15, kg = l >> 4;

  const int bt = blockIdx.x;
  const int n0 = blockIdx.y * 128;
  int s = 0;
#pragma unroll
  for (int t = 0; t < 5; ++t) s = (bt >= P.tileEnd[t]) ? t + 1 : s;
  const int tb = s ? P.tileEnd[s - 1] : 0;
  const long lrow0 = (long)(bt - tb) * 128;
  const long row0 = (long)bt * 128;

  const int srow = tid >> 1, half = tid & 1;
  const floatx4* __restrict__ selfF4 = (const floatx4*)P.selfp[s] + (lrow0 + srow) * 125;
  const ushort* __restrict__ selfB = (const ushort*)P.selfp[s] + (lrow0 + srow) * 512;
  const int swr = (srow >> 1) & 3;
  const int kg0 = half * 2;

  int aoff[4], boff[4];
#pragma unroll
  for (int mi = 0; mi < 4; ++mi) {
    const int row = wr * 64 + mi * 16 + lr;
    aoff[mi] = row * 64 + ((kg ^ ((row >> 1) & 3)) << 4);
  }
#pragma unroll
  for (int ni = 0; ni < 4; ++ni) boff[ni] = (kg * 128 + wc * 64 + ni * 16 + lr) << 4;

  floatx4 acc[4][4];
#pragma unroll
  for (int mi = 0; mi < 4; ++mi)
#pragma unroll
    for (int ni = 0; ni < 4; ++ni) acc[mi][ni] = (floatx4){0.f, 0.f, 0.f, 0.f};

  for (int ks = 0; ks < 32; ++ks) {
    __syncthreads();
    if (ks < 16) {
      bhalf8 c0, c1;
      if (!(s & 1)) {  // lvl0: fp32 + cvt
        const int f0 = ks * 8 + half * 4;
        floatx4 v[4];
#pragma unroll
        for (int q = 0; q < 4; ++q) {
          const int fi = f0 + q;
          v[q] = selfF4[(fi > 124) ? 124 : fi];
        }
        ushort h[16];
#pragma unroll
        for (int q = 0; q < 4; ++q) {
          const bool ok = (f0 + q) <= 124;
#pragma unroll
          for (int e = 0; e < 4; ++e) h[q * 4 + e] = ok ? f2bf(v[q][e]) : (ushort)0;
        }
#pragma unroll
        for (int e = 0; e < 8; ++e) { c0[e] = (short)h[e]; c1[e] = (short)h[8 + e]; }
      } else {         // lvl1: S1 bf16 direct (zero-padded)
        const int u0 = (ks * 8 + half * 4) * 4;
        c0 = *(const bhalf8*)(selfB + u0);
        c1 = *(const bhalf8*)(selfB + u0 + 8);
      }
      *(bhalf8*)((char*)As + srow * 64 + ((kg0 ^ swr) << 4)) = c0;
      *(bhalf8*)((char*)As + srow * 64 + (((kg0 + 1) ^ swr) << 4)) = c1;
    } else {
      const int k0 = (ks - 16) * 32;
#pragma unroll
      for (int it = 0; it < 2; ++it) {
        const int o = it * 4096 + tid * 16;
        const int row = o >> 6;
        const int sw = (o >> 4) & 3;
        const int kgs = sw ^ ((row >> 1) & 3);
        const ushort* g = M1 + (row0 + row) * (size_t)512 + (k0 + kgs * 8);
        gll16(g, (char*)As + it * 4096 + wid * 1024);
      }
    }
#pragma unroll
    for (int it = 0; it < 2; ++it) {
      const int cell = it * 256 + tid;
      const int bkg = cell >> 7;
      const int n = cell & 127;
      const ushort* g = W0p + ((size_t)(ks * 4 + bkg) * 256 + (n0 + n)) * 8;
      gll16(g, (char*)Bs + it * 4096 + wid * 1024);
    }
    __syncthreads();

    bhalf8 af[4], bfr[4];
#pragma unroll
    for (int mi = 0; mi < 4; ++mi) af[mi] = *(const bhalf8*)((const char*)As + aoff[mi]);
#pragma unroll
    for (int ni = 0; ni < 4; ++ni) bfr[ni] = *(const bhalf8*)((const char*)Bs + boff[ni]);
#pragma unroll
    for (int mi = 0; mi < 4; ++mi)
#pragma unroll
      for (int ni = 0; ni < 4; ++ni)
        acc[mi][ni] = __builtin_amdgcn_mfma_f32_16x16x32_bf16(af[mi], bfr[ni], acc[mi][ni], 0, 0, 0);
  }

#pragma unroll
  for (int mi = 0; mi < 4; ++mi)
#pragma unroll
    for (int ni = 0; ni < 4; ++ni) {
      const floatx4 v = acc[mi][ni];
      const int gcol = n0 + wc * 64 + ni * 16 + lr;
#pragma unroll
      for (int r = 0; r < 4; ++r) {
        const long grow = row0 + wr * 64 + mi * 16 + kg * 4 + r;
        H1[grow * 256 + gcol] = f2bf(fmaxf(v[r], 0.f));
      }
    }
}

// ---------------- agg1: H1 bf16 -> A2 [1792][512] bf16 (self | mean10) -------
__global__ __launch_bounds__(256) void agg1_pack(const ushort* __restrict__ H1, ushort* __restrict__ A2,
                                                 long total) {
  const long stride = (long)gridDim.x * 256;
  for (long idx = (long)blockIdx.x * 256 + threadIdx.x; idx < total; idx += stride) {
    const bool g1 = idx >= 32768, g2 = idx >= 65536;
    const long base = g2 ? 65536 : (g1 ? 32768 : 0);
    const int selfo = g2 ? 5632 : (g1 ? 2816 : 0);
    const int neigho = g2 ? 6912 : (g1 ? 3072 : 256);
    const int outo = g2 ? 512 : (g1 ? 256 : 0);
    const long li = idx - base;
    const long r = li >> 7;
    const int c = (int)(li & 127);
    const ushort4* H = (const ushort4*)H1;
    ushort4 ov;
    if (c < 64) {
      ov = H[((long)selfo + r) * 64 + c];
    } else {
      const int j = c - 64;
      float ax = 0.f, ay = 0.f, az = 0.f, aw = 0.f;
#pragma unroll
      for (int k = 0; k < 10; ++k) {
        const ushort4 v = H[((long)neigho + r * 10 + k) * 64 + j];
        ax += bf2f(v.x); ay += bf2f(v.y); az += bf2f(v.z); aw += bf2f(v.w);
      }
      ov.x = f2bf(ax * 0.1f); ov.y = f2bf(ay * 0.1f);
      ov.z = f2bf(az * 0.1f); ov.w = f2bf(aw * 0.1f);
    }
    ((ushort4*)A2)[((long)outo + r) * 128 + c] = ov;
  }
}

// ---------------- MFMA GEMM (layer1): C = relu(A @ Bpacked) ------------------
template <int BM, int BN, int MI, int NI, bool OUT_BF16>
__global__ __launch_bounds__(256) void gemm_mfma(const ushort* __restrict__ A,
                                                 const ushort* __restrict__ Bp,
                                                 void* __restrict__ Cout, int K, int Nfull) {
  __shared__ ushort As[BM * 32];
  __shared__ ushort Bs[BN * 32];

  const int tid = threadIdx.x;
  const int wid = tid >> 6, l = tid & 63;
  const int wr = wid >> 1, wc = wid & 1;
  const int lr = l & 15, kg = l >> 4;
  const long row0 = (long)blockIdx.x * BM;
  const int n0 = blockIdx.y * BN;

  int aoff[MI], boff[NI];
#pragma unroll
  for (int mi = 0; mi < MI; ++mi) {
    const int row = wr * (MI * 16) + mi * 16 + lr;
    aoff[mi] = row * 64 + ((kg ^ ((row >> 1) & 3)) << 4);
  }
#pragma unroll
  for (int ni = 0; ni < NI; ++ni) {
    const int cell = kg * BN + wc * (NI * 16) + ni * 16 + lr;
    boff[ni] = cell << 4;
  }

  floatx4 acc[MI][NI];
#pragma unroll
  for (int mi = 0; mi < MI; ++mi)
#pragma unroll
    for (int ni = 0; ni < NI; ++ni) acc[mi][ni] = (floatx4){0.f, 0.f, 0.f, 0.f};

  const int ksteps = K >> 5;
  for (int ks = 0; ks < ksteps; ++ks) {
    const int k0 = ks << 5;
    __syncthreads();
#pragma unroll
    for (int it = 0; it < (BM * 64) / 4096; ++it) {
      const int o = it * 4096 + tid * 16;
      const int row = o >> 6;
      const int sw = (o >> 4) & 3;
      const int kgs = sw ^ ((row >> 1) & 3);
      const ushort* g = A + (row0 + row) * (size_t)K + (k0 + kgs * 8);
      gll16(g, (char*)As + it * 4096 + wid * 1024);
    }
#pragma unroll
    for (int it = 0; it < (BN * 64) / 4096; ++it) {
      const int cell = it * 256 + tid;
      const int bkg = cell / BN;
      const int n = cell & (BN - 1);
      const ushort* g = Bp + ((size_t)(ks * 4 + bkg) * Nfull + (n0 + n)) * 8;
      gll16(g, (char*)Bs + it * 4096 + wid * 1024);
    }
    __syncthreads();

    bhalf8 af[MI], bf[NI];
#pragma unroll
    for (int mi = 0; mi < MI; ++mi) af[mi] = *(const bhalf8*)((const char*)As + aoff[mi]);
#pragma unroll
    for (int ni = 0; ni < NI; ++ni) bf[ni] = *(const bhalf8*)((const char*)Bs + boff[ni]);
#pragma unroll
    for (int mi = 0; mi < MI; ++mi)
#pragma unroll
      for (int ni = 0; ni < NI; ++ni)
        acc[mi][ni] = __builtin_amdgcn_mfma_f32_16x16x32_bf16(af[mi], bf[ni], acc[mi][ni], 0, 0, 0);
  }

#pragma unroll
  for (int mi = 0; mi < MI; ++mi)
#pragma unroll
    for (int ni = 0; ni < NI; ++ni) {
      const floatx4 v = acc[mi][ni];
      const int gcol = n0 + wc * (NI * 16) + ni * 16 + lr;
#pragma unroll
      for (int r = 0; r < 4; ++r) {
        const long grow = row0 + wr * (MI * 16) + mi * 16 + kg * 4 + r;
        const float x = fmaxf(v[r], 0.f);
        if (OUT_BF16)
          ((ushort*)Cout)[grow * Nfull + gcol] = f2bf(x);
        else
          ((float*)Cout)[grow * Nfull + gcol] = x;
      }
    }
}

extern "C" void kernel_launch(void* const* d_in, const int* in_sizes, int n_in,
                              void* d_out, int out_size, void* d_ws, size_t ws_size,
                              hipStream_t stream) {
  const float* xsrc0 = (const float*)d_in[0];
  const float* xdst0 = (const float*)d_in[1];
  const float* xneg0 = (const float*)d_in[2];
  const float* xsrc1 = (const float*)d_in[3];
  const float* xdst1 = (const float*)d_in[4];
  const float* xneg1 = (const float*)d_in[5];
  const float* xsrc2 = (const float*)d_in[6];
  const float* xdst2 = (const float*)d_in[7];
  const float* xneg2 = (const float*)d_in[8];
  const float* W0 = (const float*)d_in[9];
  const float* W1 = (const float*)d_in[10];
  float* out = (float*)d_out;

  // workspace (ushorts), 16B aligned:
  ushort* M1 = (ushort*)d_ws;        // 19712*512 = 10,092,544
  ushort* S1 = M1 + 10092544;        // 17920*512 =  9,175,040
  ushort* H1 = S1 + 9175040;         // 19712*256 =  5,046,272
  ushort* A2 = H1 + 5046272;         // 1792*512  =    917,504
  ushort* W0p = A2 + 917504;         // 262,144
  ushort* W1p = W0p + 262144;        // 65,536   (total ~51 MB)

  misc_k<<<dim3(1721), dim3(256), 0, stream>>>(W0, W1, W0p, W1p, M1, S1);

  // ---- mean stream (lvl2 first, lvl1 last + S1 side-write) ----
  {
    MSP p;
    const float* srcs[6] = {xsrc2, xdst2, xneg2, xsrc1, xdst1, xneg1};
    static const long itemEnd[6] = {320000, 640000, 2240000, 2272000, 2304000, 2464000};
    static const int outRow[6] = {256, 3072, 6912, 0, 2816, 5632};
    static const int s1Off[6] = {0, 0, 0, 0, 2560, 5120};
    for (int j = 0; j < 6; ++j) {
      p.src[j] = srcs[j];
      p.itemEnd[j] = itemEnd[j];
      p.outRow[j] = outRow[j];
      p.s1Off[j] = s1Off[j];
    }
    mean_stream<<<dim3(4813), dim3(256), 0, stream>>>(p, M1, S1);
  }

  // ---- layer0 GEMM (hybrid A) ----
  {
    G0P g;
    g.selfp[0] = xsrc0;
    g.selfp[1] = S1;
    g.selfp[2] = xdst0;
    g.selfp[3] = S1 + (size_t)2560 * 512;
    g.selfp[4] = xneg0;
    g.selfp[5] = S1 + (size_t)5120 * 512;
    static const int tileEnd[6] = {2, 22, 24, 44, 54, 154};
    for (int j = 0; j < 6; ++j) g.tileEnd[j] = tileEnd[j];
    gemm0_hybrid<<<dim3(154, 2), dim3(256), 0, stream>>>(g, M1, W0p, H1);
  }

  // ---- layer1 agg + pack ----
  agg1_pack<<<dim3(896), dim3(256), 0, stream>>>(H1, A2, 229376);

  // ---- layer1 GEMM ----
  gemm_mfma<64, 64, 2, 2, false><<<dim3(28, 2), dim3(256), 0, stream>>>(A2, W1p, out, 512, 128);
}

// Round 14
// 120.160 us; speedup vs baseline: 1.1715x; 1.1689x over previous
//
#include <hip/hip_runtime.h>

// ---------------------------------------------------------------------------
// GraphSAGE 2-layer forward, bf16 MFMA.  == FINAL: byte-identical to Round 9,
// the best measured configuration (120.6 us). ==
// Pipeline: misc (W pack + pads) -> mean_stream (mean10 -> M1, lvl1 bf16 -> S1)
//           -> gemm0_hybrid -> agg1_pack -> gemm1.
// NT policy (measured optimum, R9..R13 ledger): lvl2 streams (358 MB) NT;
// lvl1 (36 MB) plain -> retained across graph replays at L2 scale (+10 us);
// any larger plain set thrashes (-20 us).
// ---------------------------------------------------------------------------

typedef __attribute__((ext_vector_type(8))) short bhalf8;
typedef __attribute__((ext_vector_type(4))) float floatx4;

__device__ __forceinline__ ushort f2bf(float f) {
  uint32_t u = __float_as_uint(f);
  return (ushort)((u + 0x7fffu + ((u >> 16) & 1u)) >> 16);
}
__device__ __forceinline__ float bf2f(ushort u) {
  return __uint_as_float(((uint32_t)u) << 16);
}
__device__ __forceinline__ void gll16(const void* g, void* l) {
  __builtin_amdgcn_global_load_lds((const __attribute__((address_space(1))) void*)g,
                                   (__attribute__((address_space(3))) void*)l, 16, 0, 0);
}

// ------- misc: grid 1721 = 1280 (W pack) | 231 (M1 pad) | 210 (S1 pad) ------
__global__ __launch_bounds__(256) void misc_k(const float* __restrict__ W0, const float* __restrict__ W1,
                                              ushort* __restrict__ W0p, ushort* __restrict__ W1p,
                                              ushort* __restrict__ M1, ushort* __restrict__ S1) {
  const int b = blockIdx.x, tid = threadIdx.x;
  if (b < 1280) {
    const int idx = b * 256 + tid;
    if (idx < 262144) {  // W0p: [kstp(32)][kg(4)][n(256)][i(8)]
      const int i = idx & 7, n = (idx >> 3) & 255, kgv = (idx >> 11) & 3, kstp = idx >> 13;
      const int k = kstp * 32 + kgv * 8 + i;
      int srcr;
      if (k < 512) srcr = (k < 500) ? k : -1;
      else { const int k2 = k - 512; srcr = (k2 < 500) ? 500 + k2 : -1; }
      W0p[idx] = (srcr >= 0) ? f2bf(W0[srcr * 256 + n]) : (ushort)0;
    } else {             // W1p: [kstp(16)][kg(4)][n(128)][i(8)]
      const int j = idx - 262144;
      const int i = j & 7, n = (j >> 3) & 127, kgv = (j >> 10) & 3, kstp = j >> 12;
      const int k = kstp * 32 + kgv * 8 + i;
      W1p[j] = f2bf(W1[k * 128 + n]);
    }
  } else if (b < 1511) {  // M1 pad cols [125,128) f4 over 19712 rows
    const int p = (b - 1280) * 256 + tid;  // < 59136
    const int r = p / 3, sl = p - r * 3;
    ushort4 z; z.x = 0; z.y = 0; z.z = 0; z.w = 0;
    ((ushort4*)M1)[(long)r * 128 + 125 + sl] = z;
  } else {                // S1 pad cols [125,128) f4 over 17920 rows
    const int p = (b - 1511) * 256 + tid;  // < 53760
    const int r = p / 3, sl = p - r * 3;
    ushort4 z; z.x = 0; z.y = 0; z.z = 0; z.w = 0;
    ((ushort4*)S1)[(long)r * 128 + 125 + sl] = z;
  }
}

// ------- mean_stream: items = output f4 cols, order lvl2 then lvl1 ----------
// slots p=0..5 -> {src1o(xsrc2), dst1o(xdst2), neg1o(xneg2); src0o,dst0o,neg0o from lvl1}
// itemEnd {320000,640000,2240000,2272000,2304000,2464000}; HALF=1232000.
// Thread does items i and i+HALF (item1 always lvl2 -> NT). lvl1 items (p>=3)
// side-write bf16 rows to S1 and use plain loads (L2-retained across replays).
struct MSP {
  const float* src[6];   // {xsrc2,xdst2,xneg2,xsrc1,xdst1,xneg1}
  long itemEnd[6];
  int outRow[6];         // {256,3072,6912,0,2816,5632}
  int s1Off[6];          // {0,0,0,0,2560,5120}
};

__global__ __launch_bounds__(256, 4) void mean_stream(MSP P, ushort* __restrict__ M1,
                                                      ushort* __restrict__ S1) {
  long i = (long)blockIdx.x * 256 + threadIdx.x;
  if (i >= 1232000) i = 1231999;
  // item1 (always lvl2)
  int p1 = 0;
#pragma unroll
  for (int t = 0; t < 2; ++t) p1 = (i >= P.itemEnd[t]) ? t + 1 : p1;
  const long b1 = p1 ? P.itemEnd[p1 - 1] : 0;
  const int l1 = (int)(i - b1);
  const int r1 = l1 / 125, j1 = l1 - r1 * 125;
  const floatx4* __restrict__ sp1 = (const floatx4*)P.src[p1] + (long)r1 * 1250 + j1;
  // item2
  const long i2 = i + 1232000;
  int p2 = 2;
#pragma unroll
  for (int t = 2; t < 5; ++t) p2 = (i2 >= P.itemEnd[t]) ? t + 1 : p2;
  const long b2 = P.itemEnd[p2 - 1];
  const int l2 = (int)(i2 - b2);
  const int r2 = l2 / 125, j2 = l2 - r2 * 125;
  const floatx4* __restrict__ sp2 = (const floatx4*)P.src[p2] + (long)r2 * 1250 + j2;

  floatx4 t1[10], t2[10];
#pragma unroll
  for (int k = 0; k < 10; ++k) t1[k] = __builtin_nontemporal_load(sp1 + (long)k * 125);
  const bool lvl1 = p2 >= 3;
  if (!lvl1) {
#pragma unroll
    for (int k = 0; k < 10; ++k) t2[k] = __builtin_nontemporal_load(sp2 + (long)k * 125);
  } else {
#pragma unroll
    for (int k = 0; k < 10; ++k) t2[k] = sp2[(long)k * 125];
  }

  const floatx4 a1 =
      ((((t1[0] + t1[1]) + (t1[2] + t1[3])) + ((t1[4] + t1[5]) + (t1[6] + t1[7]))) + (t1[8] + t1[9])) * 0.1f;
  ushort4 o1;
  o1.x = f2bf(a1.x); o1.y = f2bf(a1.y); o1.z = f2bf(a1.z); o1.w = f2bf(a1.w);
  ((ushort4*)M1)[((long)P.outRow[p1] + r1) * 128 + j1] = o1;

  if (lvl1) {  // side-write bf16 casts of the 10 lvl1 rows into S1
    const long srow = (long)P.s1Off[p2] + (long)r2 * 10;
#pragma unroll
    for (int k = 0; k < 10; ++k) {
      ushort4 c;
      c.x = f2bf(t2[k].x); c.y = f2bf(t2[k].y); c.z = f2bf(t2[k].z); c.w = f2bf(t2[k].w);
      ((ushort4*)S1)[(srow + k) * 128 + j2] = c;
    }
  }
  const floatx4 a2 =
      ((((t2[0] + t2[1]) + (t2[2] + t2[3])) + ((t2[4] + t2[5]) + (t2[6] + t2[7]))) + (t2[8] + t2[9])) * 0.1f;
  ushort4 o2;
  o2.x = f2bf(a2.x); o2.y = f2bf(a2.y); o2.z = f2bf(a2.z); o2.w = f2bf(a2.w);
  ((ushort4*)M1)[((long)P.outRow[p2] + r2) * 128 + j2] = o2;
}

// ------- gemm0_hybrid: H1 = relu([self | M1] @ W0p), 128x128 tile -----------
struct G0P {
  const void* selfp[6];  // {xsrc0, S1+0, xdst0, S1+2560*512, xneg0, S1+5120*512}
  int tileEnd[6];        // {2,22,24,44,54,154}
};

__global__ __launch_bounds__(256) void gemm0_hybrid(G0P P, const ushort* __restrict__ M1,
                                                    const ushort* __restrict__ W0p,
                                                    ushort* __restrict__ H1) {
  __shared__ ushort As[128 * 32];
  __shared__ ushort Bs[128 * 32];

  const int tid = threadIdx.x;
  const int wid = tid >> 6, l = tid & 63;
  const int wr = wid >> 1, wc = wid & 1;
  const int lr = l & 15, kg = l >> 4;

  const int bt = blockIdx.x;
  const int n0 = blockIdx.y * 128;
  int s = 0;
#pragma unroll
  for (int t = 0; t < 5; ++t) s = (bt >= P.tileEnd[t]) ? t + 1 : s;
  const int tb = s ? P.tileEnd[s - 1] : 0;
  const long lrow0 = (long)(bt - tb) * 128;
  const long row0 = (long)bt * 128;

  const int srow = tid >> 1, half = tid & 1;
  const floatx4* __restrict__ selfF4 = (const floatx4*)P.selfp[s] + (lrow0 + srow) * 125;
  const ushort* __restrict__ selfB = (const ushort*)P.selfp[s] + (lrow0 + srow) * 512;
  const int swr = (srow >> 1) & 3;
  const int kg0 = half * 2;

  int aoff[4], boff[4];
#pragma unroll
  for (int mi = 0; mi < 4; ++mi) {
    const int row = wr * 64 + mi * 16 + lr;
    aoff[mi] = row * 64 + ((kg ^ ((row >> 1) & 3)) << 4);
  }
#pragma unroll
  for (int ni = 0; ni < 4; ++ni) boff[ni] = (kg * 128 + wc * 64 + ni * 16 + lr) << 4;

  floatx4 acc[4][4];
#pragma unroll
  for (int mi = 0; mi < 4; ++mi)
#pragma unroll
    for (int ni = 0; ni < 4; ++ni) acc[mi][ni] = (floatx4){0.f, 0.f, 0.f, 0.f};

  for (int ks = 0; ks < 32; ++ks) {
    __syncthreads();
    if (ks < 16) {
      bhalf8 c0, c1;
      if (!(s & 1)) {  // lvl0: fp32 + cvt
        const int f0 = ks * 8 + half * 4;
        floatx4 v[4];
#pragma unroll
        for (int q = 0; q < 4; ++q) {
          const int fi = f0 + q;
          v[q] = selfF4[(fi > 124) ? 124 : fi];
        }
        ushort h[16];
#pragma unroll
        for (int q = 0; q < 4; ++q) {
          const bool ok = (f0 + q) <= 124;
#pragma unroll
          for (int e = 0; e < 4; ++e) h[q * 4 + e] = ok ? f2bf(v[q][e]) : (ushort)0;
        }
#pragma unroll
        for (int e = 0; e < 8; ++e) { c0[e] = (short)h[e]; c1[e] = (short)h[8 + e]; }
      } else {         // lvl1: S1 bf16 direct (zero-padded)
        const int u0 = (ks * 8 + half * 4) * 4;
        c0 = *(const bhalf8*)(selfB + u0);
        c1 = *(const bhalf8*)(selfB + u0 + 8);
      }
      *(bhalf8*)((char*)As + srow * 64 + ((kg0 ^ swr) << 4)) = c0;
      *(bhalf8*)((char*)As + srow * 64 + (((kg0 + 1) ^ swr) << 4)) = c1;
    } else {
      const int k0 = (ks - 16) * 32;
#pragma unroll
      for (int it = 0; it < 2; ++it) {
        const int o = it * 4096 + tid * 16;
        const int row = o >> 6;
        const int sw = (o >> 4) & 3;
        const int kgs = sw ^ ((row >> 1) & 3);
        const ushort* g = M1 + (row0 + row) * (size_t)512 + (k0 + kgs * 8);
        gll16(g, (char*)As + it * 4096 + wid * 1024);
      }
    }
#pragma unroll
    for (int it = 0; it < 2; ++it) {
      const int cell = it * 256 + tid;
      const int bkg = cell >> 7;
      const int n = cell & 127;
      const ushort* g = W0p + ((size_t)(ks * 4 + bkg) * 256 + (n0 + n)) * 8;
      gll16(g, (char*)Bs + it * 4096 + wid * 1024);
    }
    __syncthreads();

    bhalf8 af[4], bfr[4];
#pragma unroll
    for (int mi = 0; mi < 4; ++mi) af[mi] = *(const bhalf8*)((const char*)As + aoff[mi]);
#pragma unroll
    for (int ni = 0; ni < 4; ++ni) bfr[ni] = *(const bhalf8*)((const char*)Bs + boff[ni]);
#pragma unroll
    for (int mi = 0; mi < 4; ++mi)
#pragma unroll
      for (int ni = 0; ni < 4; ++ni)
        acc[mi][ni] = __builtin_amdgcn_mfma_f32_16x16x32_bf16(af[mi], bfr[ni], acc[mi][ni], 0, 0, 0);
  }

#pragma unroll
  for (int mi = 0; mi < 4; ++mi)
#pragma unroll
    for (int ni = 0; ni < 4; ++ni) {
      const floatx4 v = acc[mi][ni];
      const int gcol = n0 + wc * 64 + ni * 16 + lr;
#pragma unroll
      for (int r = 0; r < 4; ++r) {
        const long grow = row0 + wr * 64 + mi * 16 + kg * 4 + r;
        H1[grow * 256 + gcol] = f2bf(fmaxf(v[r], 0.f));
      }
    }
}

// ---------------- agg1: H1 bf16 -> A2 [1792][512] bf16 (self | mean10) -------
__global__ __launch_bounds__(256) void agg1_pack(const ushort* __restrict__ H1, ushort* __restrict__ A2,
                                                 long total) {
  const long stride = (long)gridDim.x * 256;
  for (long idx = (long)blockIdx.x * 256 + threadIdx.x; idx < total; idx += stride) {
    const bool g1 = idx >= 32768, g2 = idx >= 65536;
    const long base = g2 ? 65536 : (g1 ? 32768 : 0);
    const int selfo = g2 ? 5632 : (g1 ? 2816 : 0);
    const int neigho = g2 ? 6912 : (g1 ? 3072 : 256);
    const int outo = g2 ? 512 : (g1 ? 256 : 0);
    const long li = idx - base;
    const long r = li >> 7;
    const int c = (int)(li & 127);
    const ushort4* H = (const ushort4*)H1;
    ushort4 ov;
    if (c < 64) {
      ov = H[((long)selfo + r) * 64 + c];
    } else {
      const int j = c - 64;
      float ax = 0.f, ay = 0.f, az = 0.f, aw = 0.f;
#pragma unroll
      for (int k = 0; k < 10; ++k) {
        const ushort4 v = H[((long)neigho + r * 10 + k) * 64 + j];
        ax += bf2f(v.x); ay += bf2f(v.y); az += bf2f(v.z); aw += bf2f(v.w);
      }
      ov.x = f2bf(ax * 0.1f); ov.y = f2bf(ay * 0.1f);
      ov.z = f2bf(az * 0.1f); ov.w = f2bf(aw * 0.1f);
    }
    ((ushort4*)A2)[((long)outo + r) * 128 + c] = ov;
  }
}

// ---------------- MFMA GEMM (layer1): C = relu(A @ Bpacked) ------------------
template <int BM, int BN, int MI, int NI, bool OUT_BF16>
__global__ __launch_bounds__(256) void gemm_mfma(const ushort* __restrict__ A,
                                                 const ushort* __restrict__ Bp,
                                                 void* __restrict__ Cout, int K, int Nfull) {
  __shared__ ushort As[BM * 32];
  __shared__ ushort Bs[BN * 32];

  const int tid = threadIdx.x;
  const int wid = tid >> 6, l = tid & 63;
  const int wr = wid >> 1, wc = wid & 1;
  const int lr = l & 15, kg = l >> 4;
  const long row0 = (long)blockIdx.x * BM;
  const int n0 = blockIdx.y * BN;

  int aoff[MI], boff[NI];
#pragma unroll
  for (int mi = 0; mi < MI; ++mi) {
    const int row = wr * (MI * 16) + mi * 16 + lr;
    aoff[mi] = row * 64 + ((kg ^ ((row >> 1) & 3)) << 4);
  }
#pragma unroll
  for (int ni = 0; ni < NI; ++ni) {
    const int cell = kg * BN + wc * (NI * 16) + ni * 16 + lr;
    boff[ni] = cell << 4;
  }

  floatx4 acc[MI][NI];
#pragma unroll
  for (int mi = 0; mi < MI; ++mi)
#pragma unroll
    for (int ni = 0; ni < NI; ++ni) acc[mi][ni] = (floatx4){0.f, 0.f, 0.f, 0.f};

  const int ksteps = K >> 5;
  for (int ks = 0; ks < ksteps; ++ks) {
    const int k0 = ks << 5;
    __syncthreads();
#pragma unroll
    for (int it = 0; it < (BM * 64) / 4096; ++it) {
      const int o = it * 4096 + tid * 16;
      const int row = o >> 6;
      const int sw = (o >> 4) & 3;
      const int kgs = sw ^ ((row >> 1) & 3);
      const ushort* g = A + (row0 + row) * (size_t)K + (k0 + kgs * 8);
      gll16(g, (char*)As + it * 4096 + wid * 1024);
    }
#pragma unroll
    for (int it = 0; it < (BN * 64) / 4096; ++it) {
      const int cell = it * 256 + tid;
      const int bkg = cell / BN;
      const int n = cell & (BN - 1);
      const ushort* g = Bp + ((size_t)(ks * 4 + bkg) * Nfull + (n0 + n)) * 8;
      gll16(g, (char*)Bs + it * 4096 + wid * 1024);
    }
    __syncthreads();

    bhalf8 af[MI], bf[NI];
#pragma unroll
    for (int mi = 0; mi < MI; ++mi) af[mi] = *(const bhalf8*)((const char*)As + aoff[mi]);
#pragma unroll
    for (int ni = 0; ni < NI; ++ni) bf[ni] = *(const bhalf8*)((const char*)Bs + boff[ni]);
#pragma unroll
    for (int mi = 0; mi < MI; ++mi)
#pragma unroll
      for (int ni = 0; ni < NI; ++ni)
        acc[mi][ni] = __builtin_amdgcn_mfma_f32_16x16x32_bf16(af[mi], bf[ni], acc[mi][ni], 0, 0, 0);
  }

#pragma unroll
  for (int mi = 0; mi < MI; ++mi)
#pragma unroll
    for (int ni = 0; ni < NI; ++ni) {
      const floatx4 v = acc[mi][ni];
      const int gcol = n0 + wc * (NI * 16) + ni * 16 + lr;
#pragma unroll
      for (int r = 0; r < 4; ++r) {
        const long grow = row0 + wr * (MI * 16) + mi * 16 + kg * 4 + r;
        const float x = fmaxf(v[r], 0.f);
        if (OUT_BF16)
          ((ushort*)Cout)[grow * Nfull + gcol] = f2bf(x);
        else
          ((float*)Cout)[grow * Nfull + gcol] = x;
      }
    }
}

extern "C" void kernel_launch(void* const* d_in, const int* in_sizes, int n_in,
                              void* d_out, int out_size, void* d_ws, size_t ws_size,
                              hipStream_t stream) {
  const float* xsrc0 = (const float*)d_in[0];
  const float* xdst0 = (const float*)d_in[1];
  const float* xneg0 = (const float*)d_in[2];
  const float* xsrc1 = (const float*)d_in[3];
  const float* xdst1 = (const float*)d_in[4];
  const float* xneg1 = (const float*)d_in[5];
  const float* xsrc2 = (const float*)d_in[6];
  const float* xdst2 = (const float*)d_in[7];
  const float* xneg2 = (const float*)d_in[8];
  const float* W0 = (const float*)d_in[9];
  const float* W1 = (const float*)d_in[10];
  float* out = (float*)d_out;

  // workspace (ushorts), 16B aligned:
  ushort* M1 = (ushort*)d_ws;        // 19712*512 = 10,092,544
  ushort* S1 = M1 + 10092544;        // 17920*512 =  9,175,040
  ushort* H1 = S1 + 9175040;         // 19712*256 =  5,046,272
  ushort* A2 = H1 + 5046272;         // 1792*512  =    917,504
  ushort* W0p = A2 + 917504;         // 262,144
  ushort* W1p = W0p + 262144;        // 65,536   (total ~51 MB)

  misc_k<<<dim3(1721), dim3(256), 0, stream>>>(W0, W1, W0p, W1p, M1, S1);

  // ---- mean stream (lvl2 first, lvl1 last + S1 side-write) ----
  {
    MSP p;
    const float* srcs[6] = {xsrc2, xdst2, xneg2, xsrc1, xdst1, xneg1};
    static const long itemEnd[6] = {320000, 640000, 2240000, 2272000, 2304000, 2464000};
    static const int outRow[6] = {256, 3072, 6912, 0, 2816, 5632};
    static const int s1Off[6] = {0, 0, 0, 0, 2560, 5120};
    for (int j = 0; j < 6; ++j) {
      p.src[j] = srcs[j];
      p.itemEnd[j] = itemEnd[j];
      p.outRow[j] = outRow[j];
      p.s1Off[j] = s1Off[j];
    }
    mean_stream<<<dim3(4813), dim3(256), 0, stream>>>(p, M1, S1);
  }

  // ---- layer0 GEMM (hybrid A) ----
  {
    G0P g;
    g.selfp[0] = xsrc0;
    g.selfp[1] = S1;
    g.selfp[2] = xdst0;
    g.selfp[3] = S1 + (size_t)2560 * 512;
    g.selfp[4] = xneg0;
    g.selfp[5] = S1 + (size_t)5120 * 512;
    static const int tileEnd[6] = {2, 22, 24, 44, 54, 154};
    for (int j = 0; j < 6; ++j) g.tileEnd[j] = tileEnd[j];
    gemm0_hybrid<<<dim3(154, 2), dim3(256), 0, stream>>>(g, M1, W0p, H1);
  }

  // ---- layer1 agg + pack ----
  agg1_pack<<<dim3(896), dim3(256), 0, stream>>>(H1, A2, 229376);

  // ---- layer1 GEMM ----
  gemm_mfma<64, 64, 2, 2, false><<<dim3(28, 2), dim3(256), 0, stream>>>(A2, W1p, out, 512, 128);
}